// Round 4
// baseline (271.748 us; speedup 1.0000x reference)
//
#include <hip/hip_runtime.h>

// Workspace layout (float offsets)
#define WS_M2 0          // 16384 floats  (512 x 32)
#define WS_N2 16384      // 2048  floats  (64 x 32)
#define WS_WT 18432      // 131072 floats (32 x 4096), W transposed: Wt[r*4096+o]
#define WS_Z  149504     // 32768 floats  (1024 x 32)

// ---------------------------------------------------------------------------
// Kernel A: collapse TT factor chains into small dense matrices.
// ---------------------------------------------------------------------------
__global__ __launch_bounds__(256) void precompute_kernel(
    const float* __restrict__ f0, const float* __restrict__ f1,
    const float* __restrict__ f2, const float* __restrict__ f3,
    const float* __restrict__ f4, const float* __restrict__ g0,
    const float* __restrict__ g1, const float* __restrict__ g2,
    float* __restrict__ ws)
{
    __shared__ float sA[8192];
    const int t = threadIdx.x;
    const int blk = blockIdx.x;
    if (blk < 8) {
        for (int i = t; i < 2048; i += 256) {
            int a01 = i >> 5, r2 = i & 31;
            int a0 = a01 >> 3, a1 = a01 & 7;
            float s = 0.f;
            #pragma unroll
            for (int r1 = 0; r1 < 32; ++r1)
                s += f0[a0*32 + r1] * f1[r1*256 + a1*32 + r2];
            sA[i] = s;
        }
        __syncthreads();
        for (int i = t; i < 2048; i += 256) {
            int a012 = blk*64 + (i >> 5), r3 = i & 31;
            int a01 = a012 >> 3, a2 = a012 & 7;
            float s = 0.f;
            #pragma unroll
            for (int r2 = 0; r2 < 32; ++r2)
                s += sA[a01*32 + r2] * f2[r2*256 + a2*32 + r3];
            ws[WS_M2 + a012*32 + r3] = s;
        }
    } else if (blk == 8) {
        for (int i = t; i < 2048; i += 256) {
            int a34 = i >> 5, s2 = i & 31;
            int a3 = a34 >> 3, a4 = a34 & 7;
            float s = 0.f;
            #pragma unroll
            for (int s1 = 0; s1 < 32; ++s1)
                s += f3[a3*32 + s1] * f4[s1*256 + a4*32 + s2];
            ws[WS_N2 + i] = s;
        }
    } else {
        const int j = blk - 9;   // 0..31, o-slice
        for (int i = t; i < 8192; i += 256) {
            int o01 = i >> 5, q = i & 31;
            int o0 = o01 >> 4, o1 = o01 & 15;
            float s = 0.f;
            #pragma unroll
            for (int p = 0; p < 32; ++p)
                s += g0[o0*32 + p] * g1[p*512 + o1*32 + q];
            sA[i] = s;
        }
        __syncthreads();
        for (int i = t; i < 4096; i += 256) {
            int o = j*128 + (i >> 5);
            int r = i & 31;
            int o01 = o >> 4, o2 = o & 15;
            float s = 0.f;
            #pragma unroll
            for (int q = 0; q < 32; ++q)
                s += sA[o01*32 + q] * g2[q*512 + o2*32 + r];
            ws[WS_WT + r*4096 + o] = s;
        }
    }
}

// ---------------------------------------------------------------------------
// Kernel B: one block per batch element, software-pipelined staging.
//   phase 1: T3[m,r] = sum_k x[b,k,m]*M2[k,r]  (m=64,k=512,r=32)
//     Register prefetch of chunk c+1 issued right after the barrier that
//     releases the LDS buffer, BEFORE computing chunk c -> global latency
//     hidden under compute; the vmcnt(0) drain lands after ~1600 cyc.
//   8m x 4r register tile, k split over the 4 waves, LDS reduce, then
//   phase 3 (T5) and phase 4 (z).
// LDS: 34 KB -> 4 blocks/CU; grid = exactly 4 blocks/CU.
// ---------------------------------------------------------------------------
__global__ __launch_bounds__(256, 4) void main_kernel(
    const float* __restrict__ x, const float* __restrict__ core,
    const float* __restrict__ ws, float* __restrict__ zout)
{
    __shared__ float buf[8192];   // phase1: x-chunk[0..4096)+M2-chunk[4096..6144)
                                  // reduce: 4 x 2048 partial T3
                                  // phase3: T3[0..2048)+N2[2048..4096)+T5[4096..5120)
    __shared__ float spart[512];
    const int t = threadIdx.x;
    const int b = blockIdx.x;

    const int tk = t >> 6;         // wave id = k-sixteenth within chunk
    const int tm = (t >> 3) & 7;   // m-group of 8
    const int tr = t & 7;          // r-group of 4

    float4* buf4 = (float4*)buf;
    const float4* x4  = (const float4*)(x + (size_t)b * 32768);
    const float4* m24 = (const float4*)(ws + WS_M2);

    float acc[8][4];
    #pragma unroll
    for (int i = 0; i < 8; ++i)
        #pragma unroll
        for (int j = 0; j < 4; ++j) acc[i][j] = 0.f;

    // prefetch chunk 0 into registers
    float4 px0, px1, px2, px3, pm0, pm1;
    px0 = x4[t]; px1 = x4[256 + t]; px2 = x4[512 + t]; px3 = x4[768 + t];
    pm0 = m24[t]; pm1 = m24[256 + t];

    for (int c = 0; c < 8; ++c) {
        // store prefetched chunk into LDS
        buf4[t] = px0; buf4[256 + t] = px1;
        buf4[512 + t] = px2; buf4[768 + t] = px3;
        buf4[1024 + t] = pm0; buf4[1280 + t] = pm1;
        __syncthreads();

        // issue prefetch for chunk c+1 (overlaps compute below)
        if (c < 7) {
            const float4* xs = x4 + (c + 1) * 1024;
            px0 = xs[t]; px1 = xs[256 + t]; px2 = xs[512 + t]; px3 = xs[768 + t];
            const float4* ms = m24 + (c + 1) * 512;
            pm0 = ms[t]; pm1 = ms[256 + t];
        }

        #pragma unroll 4
        for (int k0 = 0; k0 < 16; ++k0) {
            const int k = tk*16 + k0;
            float4 xa = buf4[k*16 + tm*2];
            float4 xb = buf4[k*16 + tm*2 + 1];
            float4 wv = buf4[1024 + k*8 + tr];
            const float xm[8] = {xa.x,xa.y,xa.z,xa.w, xb.x,xb.y,xb.z,xb.w};
            #pragma unroll
            for (int i = 0; i < 8; ++i) {
                acc[i][0] += xm[i]*wv.x; acc[i][1] += xm[i]*wv.y;
                acc[i][2] += xm[i]*wv.z; acc[i][3] += xm[i]*wv.w;
            }
        }
        __syncthreads();
    }

    // write per-wave partial T3 tiles: buf[tk*2048 + m*32 + r]
    #pragma unroll
    for (int i = 0; i < 8; ++i) {
        float4 v = {acc[i][0], acc[i][1], acc[i][2], acc[i][3]};
        buf4[tk*512 + (tm*8 + i)*8 + tr] = v;
    }
    __syncthreads();

    // reduce over tk, result at buf[0..2048); reload N2 into buf[2048..4096)
    {
        float4 s0 = buf4[t*2], s1 = buf4[t*2 + 1];
        #pragma unroll
        for (int q = 1; q < 4; ++q) {
            float4 a = buf4[q*512 + t*2], c2 = buf4[q*512 + t*2 + 1];
            s0.x+=a.x; s0.y+=a.y; s0.z+=a.z; s0.w+=a.w;
            s1.x+=c2.x; s1.y+=c2.y; s1.z+=c2.z; s1.w+=c2.w;
        }
        __syncthreads();
        buf4[t*2] = s0; buf4[t*2 + 1] = s1;
        const float4* n24 = (const float4*)(ws + WS_N2);
        buf4[512 + t] = n24[t];
        buf4[768 + t] = n24[256 + t];
    }
    __syncthreads();

    // phase 3: T5[r3,s2] = sum_m T3[m,r3]*N2[m,s2] -> buf[4096..5120)
    {
        const int r3  = t >> 3;
        const int s2b = (t & 7) * 4;
        float a0=0.f, a1=0.f, a2=0.f, a3=0.f;
        #pragma unroll 8
        for (int m = 0; m < 64; ++m) {
            float av = buf[m*32 + r3];
            const float* n = &buf[2048 + m*32 + s2b];
            a0 += av*n[0]; a1 += av*n[1]; a2 += av*n[2]; a3 += av*n[3];
        }
        float* d = &buf[4096 + r3*32 + s2b];
        d[0]=a0; d[1]=a1; d[2]=a2; d[3]=a3;
    }
    __syncthreads();

    // phase 4: z[ro] = sum_k T5[k]*core[k,ro]; 16 k-slices x 16 ro-pairs
    {
        const int ro2 = t & 15;
        const int kc  = t >> 4;
        const float2* core2 = (const float2*)core;
        float s0 = 0.f, s1 = 0.f;
        const int k0 = kc * 64;
        for (int k = k0; k < k0 + 64; ++k) {
            float tv = buf[4096 + k];
            float2 cv = core2[k*16 + ro2];
            s0 += tv*cv.x; s1 += tv*cv.y;
        }
        spart[kc*32 + ro2*2 + 0] = s0;
        spart[kc*32 + ro2*2 + 1] = s1;
    }
    __syncthreads();
    if (t < 32) {
        float s = 0.f;
        #pragma unroll
        for (int kc = 0; kc < 16; ++kc) s += spart[kc*32 + t];
        zout[b*32 + t] = s;
    }
}

// ---------------------------------------------------------------------------
// Kernel C: out[b,o] = sum_r z[b,r]*Wt[r,o] + bias[o]
// ---------------------------------------------------------------------------
__global__ __launch_bounds__(256) void out_kernel(
    const float* __restrict__ ws, const float* __restrict__ bias,
    float* __restrict__ out)
{
    __shared__ float sW[8192];   // Wt tile [32][256]
    __shared__ float sZt[2176];  // z tile transposed [32 ro][68]
    __shared__ float sB[256];
    const int t  = threadIdx.x;
    const int bt = blockIdx.x;
    const int ot = blockIdx.y;

    {
        const float4* wt4 = (const float4*)(ws + WS_WT);
        float4* d = (float4*)sW;
        #pragma unroll
        for (int i = 0; i < 8; ++i) {
            int idx = i*256 + t;
            int ro = idx >> 6, oc = idx & 63;
            d[idx] = wt4[ro*1024 + ot*64 + oc];
        }
    }
    {
        const float4* z4 = (const float4*)(ws + WS_Z) + bt*512;
        #pragma unroll
        for (int i = 0; i < 2; ++i) {
            int idx = i*256 + t;
            int bl = idx >> 3, r4 = idx & 7;
            float4 v = z4[idx];
            sZt[(r4*4 + 0)*68 + bl] = v.x;
            sZt[(r4*4 + 1)*68 + bl] = v.y;
            sZt[(r4*4 + 2)*68 + bl] = v.z;
            sZt[(r4*4 + 3)*68 + bl] = v.w;
        }
    }
    if (t < 64) {
        const float4* b4 = (const float4*)bias + ot*64;
        ((float4*)sB)[t] = b4[t];
    }
    __syncthreads();

    const int oc = t & 63;
    const int bg = t >> 6;
    const float4* sW4 = (const float4*)sW;
    const float4 bv = ((const float4*)sB)[oc];
    float4* out4 = (float4*)out;

    for (int bi = 0; bi < 16; bi += 4) {
        const int bl = bg*16 + bi;
        float4 a0 = bv, a1 = bv, a2 = bv, a3 = bv;
        #pragma unroll
        for (int ro = 0; ro < 32; ++ro) {
            float4 w = sW4[ro*64 + oc];
            float4 z = *(const float4*)&sZt[ro*68 + bl];
            a0.x += z.x*w.x; a0.y += z.x*w.y; a0.z += z.x*w.z; a0.w += z.x*w.w;
            a1.x += z.y*w.x; a1.y += z.y*w.y; a1.z += z.y*w.z; a1.w += z.y*w.w;
            a2.x += z.z*w.x; a2.y += z.z*w.y; a2.z += z.z*w.z; a2.w += z.z*w.w;
            a3.x += z.w*w.x; a3.y += z.w*w.y; a3.z += z.w*w.z; a3.w += z.w*w.w;
        }
        const size_t obase = (size_t)(bt*64 + bl) * 1024 + ot*64 + oc;
        out4[obase + 0*1024] = a0;
        out4[obase + 1*1024] = a1;
        out4[obase + 2*1024] = a2;
        out4[obase + 3*1024] = a3;
    }
}

extern "C" void kernel_launch(void* const* d_in, const int* in_sizes, int n_in,
                              void* d_out, int out_size, void* d_ws, size_t ws_size,
                              hipStream_t stream)
{
    const float* x    = (const float*)d_in[0];
    const float* f0   = (const float*)d_in[1];
    const float* f1   = (const float*)d_in[2];
    const float* f2   = (const float*)d_in[3];
    const float* f3   = (const float*)d_in[4];
    const float* f4   = (const float*)d_in[5];
    const float* core = (const float*)d_in[6];
    const float* g0   = (const float*)d_in[7];
    const float* g1   = (const float*)d_in[8];
    const float* g2   = (const float*)d_in[9];
    const float* bias = (const float*)d_in[10];
    float* ws  = (float*)d_ws;
    float* out = (float*)d_out;

    precompute_kernel<<<41, 256, 0, stream>>>(f0, f1, f2, f3, f4, g0, g1, g2, ws);
    main_kernel<<<1024, 256, 0, stream>>>(x, core, ws, ws + WS_Z);
    out_kernel<<<dim3(16, 16), 256, 0, stream>>>(ws, bias, out);
}

// Round 5
// 264.291 us; speedup vs baseline: 1.0282x; 1.0282x over previous
//
#include <hip/hip_runtime.h>

// Workspace layout (float offsets)
#define WS_M2 0          // 16384 floats  (512 x 32)
#define WS_N2 16384      // 2048  floats  (64 x 32)
#define WS_WT 18432      // 131072 floats (32 x 4096), W transposed: Wt[r*4096+o]
#define WS_Z  149504     // 32768 floats  (1024 x 32)

// ---------------------------------------------------------------------------
// Kernel A: collapse TT factor chains into small dense matrices.
// ---------------------------------------------------------------------------
__global__ __launch_bounds__(256) void precompute_kernel(
    const float* __restrict__ f0, const float* __restrict__ f1,
    const float* __restrict__ f2, const float* __restrict__ f3,
    const float* __restrict__ f4, const float* __restrict__ g0,
    const float* __restrict__ g1, const float* __restrict__ g2,
    float* __restrict__ ws)
{
    __shared__ float sA[8192];
    const int t = threadIdx.x;
    const int blk = blockIdx.x;
    if (blk < 8) {
        for (int i = t; i < 2048; i += 256) {
            int a01 = i >> 5, r2 = i & 31;
            int a0 = a01 >> 3, a1 = a01 & 7;
            float s = 0.f;
            #pragma unroll
            for (int r1 = 0; r1 < 32; ++r1)
                s += f0[a0*32 + r1] * f1[r1*256 + a1*32 + r2];
            sA[i] = s;
        }
        __syncthreads();
        for (int i = t; i < 2048; i += 256) {
            int a012 = blk*64 + (i >> 5), r3 = i & 31;
            int a01 = a012 >> 3, a2 = a012 & 7;
            float s = 0.f;
            #pragma unroll
            for (int r2 = 0; r2 < 32; ++r2)
                s += sA[a01*32 + r2] * f2[r2*256 + a2*32 + r3];
            ws[WS_M2 + a012*32 + r3] = s;
        }
    } else if (blk == 8) {
        for (int i = t; i < 2048; i += 256) {
            int a34 = i >> 5, s2 = i & 31;
            int a3 = a34 >> 3, a4 = a34 & 7;
            float s = 0.f;
            #pragma unroll
            for (int s1 = 0; s1 < 32; ++s1)
                s += f3[a3*32 + s1] * f4[s1*256 + a4*32 + s2];
            ws[WS_N2 + i] = s;
        }
    } else {
        const int j = blk - 9;   // 0..31, o-slice
        for (int i = t; i < 8192; i += 256) {
            int o01 = i >> 5, q = i & 31;
            int o0 = o01 >> 4, o1 = o01 & 15;
            float s = 0.f;
            #pragma unroll
            for (int p = 0; p < 32; ++p)
                s += g0[o0*32 + p] * g1[p*512 + o1*32 + q];
            sA[i] = s;
        }
        __syncthreads();
        for (int i = t; i < 4096; i += 256) {
            int o = j*128 + (i >> 5);
            int r = i & 31;
            int o01 = o >> 4, o2 = o & 15;
            float s = 0.f;
            #pragma unroll
            for (int q = 0; q < 32; ++q)
                s += sA[o01*32 + q] * g2[q*512 + o2*32 + r];
            ws[WS_WT + r*4096 + o] = s;
        }
    }
}

// ---------------------------------------------------------------------------
// Kernel B: one block per batch element. Barrier-free phase 1:
//   lane = m (64 lanes = 64 m).  Wave w owns k-quarter [w*128, w*128+128).
//   Per k: x[b,k,lane] is ONE coalesced per-lane dword load (exact traffic,
//   no LDS); M2[k,r] is wave-uniform -> scalar loads broadcast via SGPRs.
//   acc[r=0..31] in VGPRs. No __syncthreads in the whole k-loop: 16
//   independent waves/CU stream freely, VALU-bound.
//   Then one LDS reduce over the 4 k-quarters (transposed, pitch 65:
//   bank=(r+m)%32 -> <=2-way, free), then phase 3 (T5) and phase 4 (z).
// LDS: 8320 + 512 floats = ~35 KB -> 4 blocks/CU.
// ---------------------------------------------------------------------------
__global__ __launch_bounds__(256, 4) void main_kernel(
    const float* __restrict__ x, const float* __restrict__ core,
    const float* __restrict__ ws, float* __restrict__ zout)
{
    __shared__ float buf[8320];   // partials: w*2080 + r*65 + m  (4 regions)
                                  // after reduce: T3t in w=0 region,
                                  // N2 at [4160..6208), T5 at [6240..7264)
    __shared__ float spart[512];
    const int t = threadIdx.x;
    const int b = blockIdx.x;
    const int w    = __builtin_amdgcn_readfirstlane(t >> 6);  // wave id 0..3
    const int lane = t & 63;                                   // = m

    // ---- phase 1: T3[m, r] = sum_k x[b,k,m] * M2[k,r], k-quarter per wave
    const float* __restrict__ xw = x + (size_t)b * 32768 + w * 8192 + lane;
    const float* __restrict__ m2 = ws + WS_M2 + w * 4096;

    float acc[32];
    #pragma unroll
    for (int r = 0; r < 32; ++r) acc[r] = 0.f;

    for (int k0 = 0; k0 < 128; k0 += 8) {
        float xv[8];
        #pragma unroll
        for (int i = 0; i < 8; ++i) xv[i] = xw[(k0 + i) * 64];
        #pragma unroll
        for (int i = 0; i < 8; ++i) {
            const float* __restrict__ mr = m2 + (k0 + i) * 32;
            #pragma unroll
            for (int r = 0; r < 32; ++r) acc[r] += xv[i] * mr[r];
        }
    }

    // write per-wave partial, transposed with pitch 65 (conflict-free)
    #pragma unroll
    for (int r = 0; r < 32; ++r) buf[w*2080 + r*65 + lane] = acc[r];
    __syncthreads();

    // ---- reduce over the 4 k-quarters; final T3t lands in w=0 region
    {
        const int rr = t >> 3;         // 0..31
        const int mb = (t & 7) * 8;    // 0,8,...,56
        float s[8];
        #pragma unroll
        for (int i = 0; i < 8; ++i) {
            s[i] = buf[rr*65 + mb + i] + buf[2080 + rr*65 + mb + i]
                 + buf[4160 + rr*65 + mb + i] + buf[6240 + rr*65 + mb + i];
        }
        // each thread writes only addresses it alone read -> no barrier needed
        #pragma unroll
        for (int i = 0; i < 8; ++i) buf[rr*65 + mb + i] = s[i];
    }
    __syncthreads();

    // ---- stage N2 into [4160..6208)
    {
        const float4* n24 = (const float4*)(ws + WS_N2);
        float4* d = (float4*)(buf + 4160);
        d[t] = n24[t];
        d[256 + t] = n24[256 + t];
    }
    __syncthreads();

    // ---- phase 3: T5[r3,s2] = sum_m T3t[r3,m] * N2[m,s2] -> [6240..7264)
    {
        const int r3  = t >> 3;
        const int s2b = (t & 7) * 4;
        float a0=0.f, a1=0.f, a2=0.f, a3=0.f;
        #pragma unroll 8
        for (int m = 0; m < 64; ++m) {
            float av = buf[r3*65 + m];
            const float* n = &buf[4160 + m*32 + s2b];
            a0 += av*n[0]; a1 += av*n[1]; a2 += av*n[2]; a3 += av*n[3];
        }
        float* d = &buf[6240 + r3*32 + s2b];
        d[0]=a0; d[1]=a1; d[2]=a2; d[3]=a3;
    }
    __syncthreads();

    // ---- phase 4: z[ro] = sum_k T5[k] * core[k,ro]
    {
        const int ro2 = t & 15;
        const int kc  = t >> 4;
        const float2* core2 = (const float2*)core;
        float s0 = 0.f, s1 = 0.f;
        const int k0 = kc * 64;
        for (int k = k0; k < k0 + 64; ++k) {
            float tv = buf[6240 + k];
            float2 cv = core2[k*16 + ro2];
            s0 += tv*cv.x; s1 += tv*cv.y;
        }
        spart[kc*32 + ro2*2 + 0] = s0;
        spart[kc*32 + ro2*2 + 1] = s1;
    }
    __syncthreads();
    if (t < 32) {
        float s = 0.f;
        #pragma unroll
        for (int kc = 0; kc < 16; ++kc) s += spart[kc*32 + t];
        zout[b*32 + t] = s;
    }
}

// ---------------------------------------------------------------------------
// Kernel C: out[b,o] = sum_r z[b,r]*Wt[r,o] + bias[o]
// ---------------------------------------------------------------------------
__global__ __launch_bounds__(256) void out_kernel(
    const float* __restrict__ ws, const float* __restrict__ bias,
    float* __restrict__ out)
{
    __shared__ float sW[8192];   // Wt tile [32][256]
    __shared__ float sZt[2176];  // z tile transposed [32 ro][68]
    __shared__ float sB[256];
    const int t  = threadIdx.x;
    const int bt = blockIdx.x;
    const int ot = blockIdx.y;

    {
        const float4* wt4 = (const float4*)(ws + WS_WT);
        float4* d = (float4*)sW;
        #pragma unroll
        for (int i = 0; i < 8; ++i) {
            int idx = i*256 + t;
            int ro = idx >> 6, oc = idx & 63;
            d[idx] = wt4[ro*1024 + ot*64 + oc];
        }
    }
    {
        const float4* z4 = (const float4*)(ws + WS_Z) + bt*512;
        #pragma unroll
        for (int i = 0; i < 2; ++i) {
            int idx = i*256 + t;
            int bl = idx >> 3, r4 = idx & 7;
            float4 v = z4[idx];
            sZt[(r4*4 + 0)*68 + bl] = v.x;
            sZt[(r4*4 + 1)*68 + bl] = v.y;
            sZt[(r4*4 + 2)*68 + bl] = v.z;
            sZt[(r4*4 + 3)*68 + bl] = v.w;
        }
    }
    if (t < 64) {
        const float4* b4 = (const float4*)bias + ot*64;
        ((float4*)sB)[t] = b4[t];
    }
    __syncthreads();

    const int oc = t & 63;
    const int bg = t >> 6;
    const float4* sW4 = (const float4*)sW;
    const float4 bv = ((const float4*)sB)[oc];
    float4* out4 = (float4*)out;

    for (int bi = 0; bi < 16; bi += 4) {
        const int bl = bg*16 + bi;
        float4 a0 = bv, a1 = bv, a2 = bv, a3 = bv;
        #pragma unroll
        for (int ro = 0; ro < 32; ++ro) {
            float4 w = sW4[ro*64 + oc];
            float4 z = *(const float4*)&sZt[ro*68 + bl];
            a0.x += z.x*w.x; a0.y += z.x*w.y; a0.z += z.x*w.z; a0.w += z.x*w.w;
            a1.x += z.y*w.x; a1.y += z.y*w.y; a1.z += z.y*w.z; a1.w += z.y*w.w;
            a2.x += z.z*w.x; a2.y += z.z*w.y; a2.z += z.z*w.z; a2.w += z.z*w.w;
            a3.x += z.w*w.x; a3.y += z.w*w.y; a3.z += z.w*w.z; a3.w += z.w*w.w;
        }
        const size_t obase = (size_t)(bt*64 + bl) * 1024 + ot*64 + oc;
        out4[obase + 0*1024] = a0;
        out4[obase + 1*1024] = a1;
        out4[obase + 2*1024] = a2;
        out4[obase + 3*1024] = a3;
    }
}

extern "C" void kernel_launch(void* const* d_in, const int* in_sizes, int n_in,
                              void* d_out, int out_size, void* d_ws, size_t ws_size,
                              hipStream_t stream)
{
    const float* x    = (const float*)d_in[0];
    const float* f0   = (const float*)d_in[1];
    const float* f1   = (const float*)d_in[2];
    const float* f2   = (const float*)d_in[3];
    const float* f3   = (const float*)d_in[4];
    const float* f4   = (const float*)d_in[5];
    const float* core = (const float*)d_in[6];
    const float* g0   = (const float*)d_in[7];
    const float* g1   = (const float*)d_in[8];
    const float* g2   = (const float*)d_in[9];
    const float* bias = (const float*)d_in[10];
    float* ws  = (float*)d_ws;
    float* out = (float*)d_out;

    precompute_kernel<<<41, 256, 0, stream>>>(f0, f1, f2, f3, f4, g0, g1, g2, ws);
    main_kernel<<<1024, 256, 0, stream>>>(x, core, ws, ws + WS_Z);
    out_kernel<<<dim3(16, 16), 256, 0, stream>>>(ws, bias, out);
}